// Round 1
// baseline (947.433 us; speedup 1.0000x reference)
//
#include <hip/hip_runtime.h>

#define B_   16
#define T_   512
#define C_   1024
#define D_   4096
#define K_   128
#define WIN_ 8
#define NW_  (T_ / WIN_)   // 64
#define M_   (B_ * T_)     // 8192

// ---------------------------------------------------------------------------
// K0: fold b_dec into the encoder bias:  benc2[d] = b_enc[d] - sum_c b_dec[c]*W_enc[d,c]
// ---------------------------------------------------------------------------
__global__ __launch_bounds__(256) void prep_benc(
    const float* __restrict__ W_enc, const float* __restrict__ b_enc,
    const float* __restrict__ b_dec, float* __restrict__ benc2)
{
    int d = blockIdx.x;
    const float* row = W_enc + (size_t)d * C_;
    float s = 0.f;
    for (int c = threadIdx.x; c < C_; c += 256) s += row[c] * b_dec[c];
    __shared__ float red[256];
    red[threadIdx.x] = s;
    __syncthreads();
    for (int off = 128; off > 0; off >>= 1) {
        if (threadIdx.x < off) red[threadIdx.x] += red[threadIdx.x + off];
        __syncthreads();
    }
    if (threadIdx.x == 0) benc2[d] = b_enc[d] - red[0];
}

// ---------------------------------------------------------------------------
// K1: transpose W_dec (C,D) -> WdT (D,C) so decode reads are coalesced rows
// ---------------------------------------------------------------------------
__global__ void transpose_wdec(const float* __restrict__ W, float* __restrict__ WT)
{
    __shared__ float tile[32][33];
    int d0 = blockIdx.x * 32;
    int c0 = blockIdx.y * 32;
    int tx = threadIdx.x, ty = threadIdx.y;  // (32,8)
    #pragma unroll
    for (int i = 0; i < 32; i += 8)
        tile[ty + i][tx] = W[(size_t)(c0 + ty + i) * D_ + d0 + tx];
    __syncthreads();
    #pragma unroll
    for (int i = 0; i < 32; i += 8)
        WT[(size_t)(d0 + ty + i) * C_ + c0 + tx] = tile[tx][ty + i];
}

// ---------------------------------------------------------------------------
// K2: fp32 encode GEMM: out_enc[m,d] = relu( x[m,:] . W_enc[d,:] + benc2[d] )
//   M=8192, N=4096, K=1024.  128x128 tile, 8x8 microtile, BK=16, 256 threads.
//   fp32 (not bf16/MFMA) because top-k window-sum gaps (~6e-3) require
//   ws error << gap; fp32 gives ~1e-6.
// ---------------------------------------------------------------------------
#define BM  128
#define BN  128
#define BK  16
#define BMP (BM + 4)   // +4 pad: keeps 16B alignment for b128 reads, 2-way-max write conflicts

__global__ __launch_bounds__(256) void encode_gemm(
    const float* __restrict__ A,    // x: (M_, C_)
    const float* __restrict__ Bw,   // W_enc: (D_, C_)
    const float* __restrict__ benc2,
    float* __restrict__ out_enc)    // (M_, D_): relu'd pre-activations (unmasked)
{
    __shared__ float As[BK][BMP];
    __shared__ float Bs[BK][BMP];
    int bn = blockIdx.x;            // 0..31
    int bm = blockIdx.y;            // 0..63
    int tid = threadIdx.x;
    int tx = tid % 16, ty = tid / 16;
    float acc[8][8] = {};

    const float* Ablk = A  + (size_t)bm * BM * C_;
    const float* Bblk = Bw + (size_t)bn * BN * C_;
    int lr = tid / 4;             // 0..63
    int lc = (tid % 4) * 4;       // 0,4,8,12

    for (int k0 = 0; k0 < C_; k0 += BK) {
        #pragma unroll
        for (int rr = 0; rr < BM; rr += 64) {
            float4 v = *(const float4*)(Ablk + (size_t)(lr + rr) * C_ + k0 + lc);
            As[lc + 0][lr + rr] = v.x; As[lc + 1][lr + rr] = v.y;
            As[lc + 2][lr + rr] = v.z; As[lc + 3][lr + rr] = v.w;
            float4 w = *(const float4*)(Bblk + (size_t)(lr + rr) * C_ + k0 + lc);
            Bs[lc + 0][lr + rr] = w.x; Bs[lc + 1][lr + rr] = w.y;
            Bs[lc + 2][lr + rr] = w.z; Bs[lc + 3][lr + rr] = w.w;
        }
        __syncthreads();
        #pragma unroll
        for (int kk = 0; kk < BK; ++kk) {
            float a[8], b[8];
            #pragma unroll
            for (int i = 0; i < 8; i++) a[i] = As[kk][ty * 8 + i];
            #pragma unroll
            for (int i = 0; i < 8; i++) b[i] = Bs[kk][tx * 8 + i];
            #pragma unroll
            for (int i = 0; i < 8; i++)
                #pragma unroll
                for (int j = 0; j < 8; j++)
                    acc[i][j] = fmaf(a[i], b[j], acc[i][j]);
        }
        __syncthreads();
    }

    int m0 = bm * BM + ty * 8;
    int n0 = bn * BN + tx * 8;
    #pragma unroll
    for (int i = 0; i < 8; i++) {
        #pragma unroll
        for (int j = 0; j < 8; j++) {
            float v = acc[i][j] + benc2[n0 + j];
            out_enc[(size_t)(m0 + i) * D_ + n0 + j] = v > 0.f ? v : 0.f;
        }
    }
}

// ---------------------------------------------------------------------------
// K3: window sums  ws[b*NW+w, d] = sum_{j<8} enc[b*T + w*8 + j, d]
//     (ws lives in the recon region of d_out as scratch; decode overwrites later)
// ---------------------------------------------------------------------------
__global__ void window_sums(const float* __restrict__ enc, float* __restrict__ wsums)
{
    int idx = blockIdx.x * blockDim.x + threadIdx.x;   // over 1024*D_
    int d = idx & (D_ - 1);
    int wrow = idx >> 12;                              // D_=4096
    int b = wrow / NW_, w = wrow % NW_;
    const float* p = enc + ((size_t)(b * T_ + w * WIN_)) * D_ + d;
    float s = 0.f;
    #pragma unroll
    for (int j = 0; j < WIN_; j++) s += p[(size_t)j * D_];
    wsums[idx] = s;
}

// ---------------------------------------------------------------------------
// K4: exact top-K=128 of 4096 per (b,w) row via 8-bit MSB radix select.
//     Tie-break identical to jax.lax.top_k: equal values -> lowest index first.
//     Outputs: bitmask (D_/32 u32 per row) + sorted-ascending index list (K_).
// ---------------------------------------------------------------------------
__global__ __launch_bounds__(256) void topk_select(
    const float* __restrict__ wsums,
    unsigned* __restrict__ bmask,     // (1024, D_/32)
    int* __restrict__ idxlist)        // (1024, K_)
{
    int row = blockIdx.x;
    const float* ws = wsums + (size_t)row * D_;
    __shared__ unsigned keys[D_];     // 16 KB
    __shared__ int hist[256];
    __shared__ int scan[256];
    __shared__ unsigned short hbits[256];
    __shared__ unsigned sh_prefix;
    __shared__ int sh_need;
    int tid = threadIdx.x;

    for (int i = tid; i < D_; i += 256) {
        unsigned u = __float_as_uint(ws[i]);
        keys[i] = (u & 0x80000000u) ? ~u : (u | 0x80000000u);  // order-preserving
    }
    if (tid == 0) { sh_prefix = 0u; sh_need = K_; }
    __syncthreads();

    for (int pass = 0; pass < 4; ++pass) {
        int shift = 24 - pass * 8;
        unsigned pref = sh_prefix;
        unsigned pmask = (pass == 0) ? 0u : (0xFFFFFFFFu << (shift + 8));
        hist[tid] = 0;
        __syncthreads();
        for (int i = tid; i < D_; i += 256) {
            unsigned k = keys[i];
            if ((k & pmask) == pref)
                atomicAdd(&hist[(k >> shift) & 0xFF], 1);
        }
        __syncthreads();
        if (tid == 0) {
            int need = sh_need, cum = 0, b = 255;
            for (;; --b) {
                if (cum + hist[b] >= need) break;
                cum += hist[b];
            }
            sh_prefix = pref | ((unsigned)b << shift);
            sh_need = need - cum;
        }
        __syncthreads();
    }
    unsigned kth = sh_prefix;   // exact key of K-th largest
    int need_eq = sh_need;      // how many ==kth to take (lowest indices)

    // per-thread chunk of 16 consecutive d
    int base = tid * 16;
    unsigned mybits = 0;
    int eqcnt = 0;
    #pragma unroll
    for (int j = 0; j < 16; ++j) {
        unsigned k = keys[base + j];
        if (k > kth) mybits |= (1u << j);
        else if (k == kth) eqcnt++;
    }
    // inclusive scan of eq counts (Hillis-Steele)
    scan[tid] = eqcnt;
    __syncthreads();
    for (int off = 1; off < 256; off <<= 1) {
        int t = (tid >= off) ? scan[tid - off] : 0;
        __syncthreads();
        scan[tid] += t;
        __syncthreads();
    }
    int r = scan[tid] - eqcnt;   // equals before my chunk
    #pragma unroll
    for (int j = 0; j < 16; ++j) {
        unsigned k = keys[base + j];
        if (k == kth) { if (r < need_eq) mybits |= (1u << j); r++; }
    }
    hbits[tid] = (unsigned short)mybits;
    __syncthreads();
    if (tid < D_ / 32)
        bmask[(size_t)row * (D_ / 32) + tid] =
            (unsigned)hbits[2 * tid] | ((unsigned)hbits[2 * tid + 1] << 16);

    // deterministic compaction (ascending d): scan of select counts
    int selcnt = __popc(mybits);
    __syncthreads();
    scan[tid] = selcnt;
    __syncthreads();
    for (int off = 1; off < 256; off <<= 1) {
        int t = (tid >= off) ? scan[tid - off] : 0;
        __syncthreads();
        scan[tid] += t;
        __syncthreads();
    }
    int pos = scan[tid] - selcnt;
    #pragma unroll
    for (int j = 0; j < 16; ++j) {
        if (mybits & (1u << j)) idxlist[(size_t)row * K_ + pos++] = base + j;
    }
}

// ---------------------------------------------------------------------------
// K5: zero non-selected entries of encoded in place
// ---------------------------------------------------------------------------
__global__ void apply_mask(float* __restrict__ enc, const unsigned* __restrict__ bmask)
{
    size_t idx = ((size_t)blockIdx.x * blockDim.x + threadIdx.x) * 4;
    size_t m = idx >> 12;             // / D_
    int d = (int)(idx & (D_ - 1));
    int b = (int)(m / T_);
    int t = (int)(m % T_);
    int wrow = b * NW_ + (t >> 3);
    unsigned word = bmask[(size_t)wrow * (D_ / 32) + (d >> 5)];
    int sh = d & 31;
    float4 v = *(float4*)(enc + idx);
    v.x = ((word >> (sh + 0)) & 1u) ? v.x : 0.f;
    v.y = ((word >> (sh + 1)) & 1u) ? v.y : 0.f;
    v.z = ((word >> (sh + 2)) & 1u) ? v.z : 0.f;
    v.w = ((word >> (sh + 3)) & 1u) ? v.w : 0.f;
    *(float4*)(enc + idx) = v;
}

// ---------------------------------------------------------------------------
// K6: sparse decode per window: recon[t,c] = b_dec[c] + sum_{i<K} act[t,di]*WdT[di,c]
// ---------------------------------------------------------------------------
__global__ __launch_bounds__(256) void decode_win(
    const float* __restrict__ enc,
    const int* __restrict__ idxlist,
    const float* __restrict__ WdT,    // (D_, C_)
    const float* __restrict__ b_dec,
    float* __restrict__ recon)        // (M_, C_)
{
    int row = blockIdx.x;             // b*NW + w
    int b = row / NW_, w = row % NW_;
    int t0 = b * T_ + w * WIN_;
    __shared__ int sidx[K_];
    __shared__ float act[K_][WIN_];   // 4 KB, row = 32B
    int tid = threadIdx.x;
    if (tid < K_) sidx[tid] = idxlist[(size_t)row * K_ + tid];
    __syncthreads();
    if (tid < K_) {
        int d = sidx[tid];
        #pragma unroll
        for (int j = 0; j < WIN_; j++)
            act[tid][j] = enc[(size_t)(t0 + j) * D_ + d];
    }
    __syncthreads();

    float accv[WIN_][4] = {};
    int c0 = tid * 4;
    for (int i = 0; i < K_; ++i) {
        int d = sidx[i];
        float4 wv = *(const float4*)(WdT + (size_t)d * C_ + c0);
        float4 a03 = *(const float4*)(&act[i][0]);
        float4 a47 = *(const float4*)(&act[i][4]);
        float aj[8] = {a03.x, a03.y, a03.z, a03.w, a47.x, a47.y, a47.z, a47.w};
        #pragma unroll
        for (int j = 0; j < WIN_; j++) {
            accv[j][0] = fmaf(aj[j], wv.x, accv[j][0]);
            accv[j][1] = fmaf(aj[j], wv.y, accv[j][1]);
            accv[j][2] = fmaf(aj[j], wv.z, accv[j][2]);
            accv[j][3] = fmaf(aj[j], wv.w, accv[j][3]);
        }
    }
    float4 bd = *(const float4*)(b_dec + c0);
    #pragma unroll
    for (int j = 0; j < WIN_; j++) {
        float4 o;
        o.x = accv[j][0] + bd.x; o.y = accv[j][1] + bd.y;
        o.z = accv[j][2] + bd.z; o.w = accv[j][3] + bd.w;
        *(float4*)(recon + (size_t)(t0 + j) * C_ + c0) = o;
    }
}

// ---------------------------------------------------------------------------
extern "C" void kernel_launch(void* const* d_in, const int* in_sizes, int n_in,
                              void* d_out, int out_size, void* d_ws, size_t ws_size,
                              hipStream_t stream)
{
    const float* x     = (const float*)d_in[0];
    const float* W_enc = (const float*)d_in[1];
    const float* b_enc = (const float*)d_in[2];
    const float* W_dec = (const float*)d_in[3];
    const float* b_dec = (const float*)d_in[4];

    float* out   = (float*)d_out;
    float* recon = out;                      // M_*C_ floats
    float* enc   = out + (size_t)M_ * C_;    // M_*D_ floats

    // workspace: WdT (16.8 MB) + bmask (512 KB) + idxlist (512 KB) + benc2 (16 KB)
    char* ws = (char*)d_ws;
    float*    WdT     = (float*)ws;
    unsigned* bmask   = (unsigned*)(ws + (size_t)D_ * C_ * 4);
    int*      idxlist = (int*)((char*)bmask + (size_t)(B_ * NW_) * (D_ / 32) * 4);
    float*    benc2   = (float*)((char*)idxlist + (size_t)(B_ * NW_) * K_ * 4);
    float*    wsums   = recon;               // scratch in recon region (freed by K6)

    prep_benc<<<D_, 256, 0, stream>>>(W_enc, b_enc, b_dec, benc2);
    transpose_wdec<<<dim3(D_ / 32, C_ / 32), dim3(32, 8), 0, stream>>>(W_dec, WdT);
    encode_gemm<<<dim3(D_ / BN, M_ / BM), 256, 0, stream>>>(x, W_enc, benc2, enc);
    window_sums<<<(B_ * NW_ * D_) / 256, 256, 0, stream>>>(enc, wsums);
    topk_select<<<B_ * NW_, 256, 0, stream>>>(wsums, bmask, idxlist);
    apply_mask<<<(int)((size_t)M_ * D_ / 4 / 256), 256, 0, stream>>>(enc, bmask);
    decode_win<<<B_ * NW_, 256, 0, stream>>>(enc, idxlist, WdT, b_dec, recon);
}

// Round 2
// 588.328 us; speedup vs baseline: 1.6104x; 1.6104x over previous
//
#include <hip/hip_runtime.h>

#define B_   16
#define T_   512
#define C_   1024
#define D_   4096
#define K_   128
#define WIN_ 8
#define NW_  (T_ / WIN_)   // 64
#define M_   (B_ * T_)     // 8192

typedef __attribute__((ext_vector_type(8))) short bf16x8_t;
typedef __attribute__((ext_vector_type(4))) float f32x4_t;

__device__ __forceinline__ void gload16(const void* g, void* l) {
    __builtin_amdgcn_global_load_lds(
        (const __attribute__((address_space(1))) void*)g,
        (__attribute__((address_space(3))) void*)l, 16, 0, 0);
}

__device__ __forceinline__ unsigned short f2bf(float f) {
    unsigned u = __float_as_uint(f);
    unsigned r = (u + 0x7fffu + ((u >> 16) & 1u)) >> 16;
    return (unsigned short)r;
}

// ---------------------------------------------------------------------------
// K0: benc2[d] = b_enc[d] - sum_c b_dec[c]*W_enc[d,c]   (folds b_dec subtraction)
// ---------------------------------------------------------------------------
__global__ __launch_bounds__(256) void prep_benc(
    const float* __restrict__ W_enc, const float* __restrict__ b_enc,
    const float* __restrict__ b_dec, float* __restrict__ benc2)
{
    int d = blockIdx.x;
    const float* row = W_enc + (size_t)d * C_;
    float s = 0.f;
    for (int c = threadIdx.x; c < C_; c += 256) s += row[c] * b_dec[c];
    __shared__ float red[256];
    red[threadIdx.x] = s;
    __syncthreads();
    for (int off = 128; off > 0; off >>= 1) {
        if (threadIdx.x < off) red[threadIdx.x] += red[threadIdx.x + off];
        __syncthreads();
    }
    if (threadIdx.x == 0) benc2[d] = b_enc[d] - red[0];
}

// ---------------------------------------------------------------------------
// K1: fp32 -> bf16 conversion (vectorized, 8 elems/thread)
// ---------------------------------------------------------------------------
__global__ void cvt_bf16(const float* __restrict__ in, unsigned short* __restrict__ out, int n8)
{
    int i = blockIdx.x * blockDim.x + threadIdx.x;
    if (i >= n8) return;
    const float4* p = (const float4*)(in + (size_t)i * 8);
    float4 a = p[0], b = p[1];
    uint4 o;
    o.x = (unsigned)f2bf(a.x) | ((unsigned)f2bf(a.y) << 16);
    o.y = (unsigned)f2bf(a.z) | ((unsigned)f2bf(a.w) << 16);
    o.z = (unsigned)f2bf(b.x) | ((unsigned)f2bf(b.y) << 16);
    o.w = (unsigned)f2bf(b.z) | ((unsigned)f2bf(b.w) << 16);
    ((uint4*)out)[i] = o;
}

// ---------------------------------------------------------------------------
// K2: transpose W_dec (C,D) -> WdT (D,C)
// ---------------------------------------------------------------------------
__global__ void transpose_wdec(const float* __restrict__ W, float* __restrict__ WT)
{
    __shared__ float tile[32][33];
    int d0 = blockIdx.x * 32;
    int c0 = blockIdx.y * 32;
    int tx = threadIdx.x, ty = threadIdx.y;  // (32,8)
    #pragma unroll
    for (int i = 0; i < 32; i += 8)
        tile[ty + i][tx] = W[(size_t)(c0 + ty + i) * D_ + d0 + tx];
    __syncthreads();
    #pragma unroll
    for (int i = 0; i < 32; i += 8)
        WT[(size_t)(d0 + ty + i) * C_ + c0 + tx] = tile[tx][ty + i];
}

// ---------------------------------------------------------------------------
// K3: bf16 MFMA GEMM, window-sums-only epilogue.
//   ws[b*NW+w, d] = sum_{t in window} relu( x[t,:].W_enc[d,:] + benc2[d] )
//   128x128 tile, BK=32, 4 waves, 16x16x32 frags, 4x4 frags/wave.
//   LDS tiles XOR-swizzled (u ^= (m>>1)&3 on 16B chunks) via pre-swizzled
//   global source + linear global_load_lds dest (rule-21 correct pattern).
// ---------------------------------------------------------------------------
__global__ __launch_bounds__(256) void mfma_gemm_ws(
    const unsigned short* __restrict__ Abf,  // x bf16 (M_, C_)
    const unsigned short* __restrict__ Bbf,  // W_enc bf16 (D_, C_)
    const float* __restrict__ benc2,
    float* __restrict__ wsums)               // (B_*NW_, D_)
{
    __shared__ unsigned short lA[128 * 32];
    __shared__ unsigned short lB[128 * 32];
    int tid = threadIdx.x;
    int lane = tid & 63;
    int wv = tid >> 6;            // wave 0..3
    int wm = wv >> 1, wn = wv & 1;
    int bn = blockIdx.x, bm = blockIdx.y;

    f32x4_t acc[4][4];
    #pragma unroll
    for (int i = 0; i < 4; i++)
        #pragma unroll
        for (int j = 0; j < 4; j++) acc[i][j] = (f32x4_t){0.f, 0.f, 0.f, 0.f};

    const unsigned short* Ab = Abf + (size_t)bm * 128 * C_;
    const unsigned short* Bb = Bbf + (size_t)bn * 128 * C_;

    // staging: chunk slot p = q*256+tid ; physical (m = p>>2, v = p&3) holds
    // logical u = v ^ ((m>>1)&3)  (XOR involution, applied on source address)
    int m_s[2], u_s[2];
    #pragma unroll
    for (int q = 0; q < 2; q++) {
        int p = q * 256 + tid;
        int m = p >> 2, v = p & 3;
        m_s[q] = m;
        u_s[q] = v ^ ((m >> 1) & 3);
    }

    int r = lane & 15, g = lane >> 4;
    for (int k0 = 0; k0 < C_; k0 += 32) {
        __syncthreads();
        #pragma unroll
        for (int q = 0; q < 2; q++) {
            gload16(Ab + (size_t)m_s[q] * C_ + k0 + u_s[q] * 8,
                    &lA[(q * 256 + wv * 64) * 8]);
            gload16(Bb + (size_t)m_s[q] * C_ + k0 + u_s[q] * 8,
                    &lB[(q * 256 + wv * 64) * 8]);
        }
        __syncthreads();
        bf16x8_t af[4], bfr[4];
        #pragma unroll
        for (int mi = 0; mi < 4; mi++) {
            int m = wm * 64 + mi * 16 + r;
            int u = g ^ ((m >> 1) & 3);
            af[mi] = *(const bf16x8_t*)&lA[m * 32 + u * 8];
        }
        #pragma unroll
        for (int ni = 0; ni < 4; ni++) {
            int d = wn * 64 + ni * 16 + r;
            int u = g ^ ((d >> 1) & 3);
            bfr[ni] = *(const bf16x8_t*)&lB[d * 32 + u * 8];
        }
        #pragma unroll
        for (int mi = 0; mi < 4; mi++)
            #pragma unroll
            for (int ni = 0; ni < 4; ni++)
                acc[mi][ni] = __builtin_amdgcn_mfma_f32_16x16x32_bf16(
                    af[mi], bfr[ni], acc[mi][ni], 0, 0, 0);
    }

    // epilogue: C/D layout col=lane&15, row=(lane>>4)*4+reg  [m89-verified]
    int b = bm >> 2;                  // 512/128 = 4 blocks per batch
    int t_blk = (bm & 3) * 128;
    #pragma unroll
    for (int ni = 0; ni < 4; ni++) {
        int d = bn * 128 + wn * 64 + ni * 16 + r;
        float bias = benc2[d];
        #pragma unroll
        for (int mi = 0; mi < 4; mi++) {
            float s = 0.f;
            #pragma unroll
            for (int q = 0; q < 4; q++) {
                float v = acc[mi][ni][q] + bias;
                s += v > 0.f ? v : 0.f;   // 4 rows of this lane-group
            }
            float partner = __shfl_xor(s, 16);   // pair lane-groups (0,1),(2,3)
            float wsv = s + partner;
            int t0 = t_blk + wm * 64 + mi * 16;  // in-batch t base of frag
            int wrow = b * NW_ + (t0 >> 3) + (g >> 1);
            if ((g & 1) == 0)
                wsums[(size_t)wrow * D_ + d] = wsv;
        }
    }
}

// ---------------------------------------------------------------------------
// K4: fp32 fixup of window-sums near the top-K boundary.
//   Radix-select approx kth; recompute exactly (fp32) every entry with
//   |ws - kth| <= DELTA; write back. DELTA=0.15 >> 2*max bf16 ws error.
// ---------------------------------------------------------------------------
#define DELTA 0.15f
#define MAXCAND 192

__device__ __forceinline__ unsigned f2key(float f) {
    unsigned u = __float_as_uint(f);
    return (u & 0x80000000u) ? ~u : (u | 0x80000000u);
}
__device__ __forceinline__ float key2f(unsigned k) {
    unsigned u = (k & 0x80000000u) ? (k & 0x7fffffffu) : ~k;
    return __uint_as_float(u);
}

__global__ __launch_bounds__(256) void fixup_ws(
    float* __restrict__ wsums, const float* __restrict__ x,
    const float* __restrict__ W_enc, const float* __restrict__ benc2)
{
    int row = blockIdx.x;             // b*NW + w
    int b = row / NW_, w = row % NW_;
    int t0g = b * T_ + w * WIN_;
    __shared__ float wsh[D_];         // 16 KB
    __shared__ float xs[WIN_][C_];    // 32 KB
    __shared__ int hist[256];
    __shared__ unsigned sh_prefix;
    __shared__ int sh_need;
    __shared__ int cand[MAXCAND];
    __shared__ int ncand;
    int tid = threadIdx.x;

    for (int i = tid; i < D_; i += 256) wsh[i] = wsums[(size_t)row * D_ + i];
    for (int i = tid; i < WIN_ * C_; i += 256) xs[i >> 10][i & (C_ - 1)] = x[(size_t)t0g * C_ + i];
    if (tid == 0) { sh_prefix = 0u; sh_need = K_; ncand = 0; }
    __syncthreads();

    for (int pass = 0; pass < 4; ++pass) {
        int shift = 24 - pass * 8;
        unsigned pref = sh_prefix;
        unsigned pmask = (pass == 0) ? 0u : (0xFFFFFFFFu << (shift + 8));
        hist[tid] = 0;
        __syncthreads();
        for (int i = tid; i < D_; i += 256) {
            unsigned k = f2key(wsh[i]);
            if ((k & pmask) == pref)
                atomicAdd(&hist[(k >> shift) & 0xFF], 1);
        }
        __syncthreads();
        if (tid == 0) {
            int need = sh_need, cum = 0, bb = 255;
            for (;; --bb) {
                if (cum + hist[bb] >= need) break;
                cum += hist[bb];
            }
            sh_prefix = pref | ((unsigned)bb << shift);
            sh_need = need - cum;
        }
        __syncthreads();
    }
    float kthf = key2f(sh_prefix);

    for (int i = tid; i < D_; i += 256) {
        if (fabsf(wsh[i] - kthf) <= DELTA) {
            int pos = atomicAdd(&ncand, 1);
            if (pos < MAXCAND) cand[pos] = i;
        }
    }
    __syncthreads();
    int nc = ncand < MAXCAND ? ncand : MAXCAND;

    int hw = tid >> 5, ln = tid & 31;   // 8 half-waves of 32 lanes
    for (int cb = hw; cb < nc; cb += 8) {
        int d = cand[cb];
        const float* wrow = W_enc + (size_t)d * C_;
        float a[WIN_] = {0.f, 0.f, 0.f, 0.f, 0.f, 0.f, 0.f, 0.f};
        for (int c = ln; c < C_; c += 32) {
            float wc = wrow[c];
            #pragma unroll
            for (int j = 0; j < WIN_; j++) a[j] = fmaf(wc, xs[j][c], a[j]);
        }
        #pragma unroll
        for (int off = 1; off < 32; off <<= 1)
            #pragma unroll
            for (int j = 0; j < WIN_; j++) a[j] += __shfl_xor(a[j], off);
        if (ln == 0) {
            float bias = benc2[d], s = 0.f;
            #pragma unroll
            for (int j = 0; j < WIN_; j++) {
                float v = a[j] + bias;
                s += v > 0.f ? v : 0.f;
            }
            wsums[(size_t)row * D_ + d] = s;
        }
    }
}

// ---------------------------------------------------------------------------
// K5: exact top-K=128 radix select (unchanged from round 1; proven)
// ---------------------------------------------------------------------------
__global__ __launch_bounds__(256) void topk_select(
    const float* __restrict__ wsums,
    unsigned* __restrict__ bmask,
    int* __restrict__ idxlist)
{
    int row = blockIdx.x;
    const float* ws = wsums + (size_t)row * D_;
    __shared__ unsigned keys[D_];
    __shared__ int hist[256];
    __shared__ int scan[256];
    __shared__ unsigned short hbits[256];
    __shared__ unsigned sh_prefix;
    __shared__ int sh_need;
    int tid = threadIdx.x;

    for (int i = tid; i < D_; i += 256) {
        unsigned u = __float_as_uint(ws[i]);
        keys[i] = (u & 0x80000000u) ? ~u : (u | 0x80000000u);
    }
    if (tid == 0) { sh_prefix = 0u; sh_need = K_; }
    __syncthreads();

    for (int pass = 0; pass < 4; ++pass) {
        int shift = 24 - pass * 8;
        unsigned pref = sh_prefix;
        unsigned pmask = (pass == 0) ? 0u : (0xFFFFFFFFu << (shift + 8));
        hist[tid] = 0;
        __syncthreads();
        for (int i = tid; i < D_; i += 256) {
            unsigned k = keys[i];
            if ((k & pmask) == pref)
                atomicAdd(&hist[(k >> shift) & 0xFF], 1);
        }
        __syncthreads();
        if (tid == 0) {
            int need = sh_need, cum = 0, bq = 255;
            for (;; --bq) {
                if (cum + hist[bq] >= need) break;
                cum += hist[bq];
            }
            sh_prefix = pref | ((unsigned)bq << shift);
            sh_need = need - cum;
        }
        __syncthreads();
    }
    unsigned kth = sh_prefix;
    int need_eq = sh_need;

    int base = tid * 16;
    unsigned mybits = 0;
    int eqcnt = 0;
    #pragma unroll
    for (int j = 0; j < 16; ++j) {
        unsigned k = keys[base + j];
        if (k > kth) mybits |= (1u << j);
        else if (k == kth) eqcnt++;
    }
    scan[tid] = eqcnt;
    __syncthreads();
    for (int off = 1; off < 256; off <<= 1) {
        int t = (tid >= off) ? scan[tid - off] : 0;
        __syncthreads();
        scan[tid] += t;
        __syncthreads();
    }
    int rr = scan[tid] - eqcnt;
    #pragma unroll
    for (int j = 0; j < 16; ++j) {
        unsigned k = keys[base + j];
        if (k == kth) { if (rr < need_eq) mybits |= (1u << j); rr++; }
    }
    hbits[tid] = (unsigned short)mybits;
    __syncthreads();
    if (tid < D_ / 32)
        bmask[(size_t)row * (D_ / 32) + tid] =
            (unsigned)hbits[2 * tid] | ((unsigned)hbits[2 * tid + 1] << 16);

    int selcnt = __popc(mybits);
    __syncthreads();
    scan[tid] = selcnt;
    __syncthreads();
    for (int off = 1; off < 256; off <<= 1) {
        int t = (tid >= off) ? scan[tid - off] : 0;
        __syncthreads();
        scan[tid] += t;
        __syncthreads();
    }
    int pos = scan[tid] - selcnt;
    #pragma unroll
    for (int j = 0; j < 16; ++j) {
        if (mybits & (1u << j)) idxlist[(size_t)row * K_ + pos++] = base + j;
    }
}

// ---------------------------------------------------------------------------
// K6: recompute selected activations exactly (fp32), scatter into zeroed
//     encoded output + compact sel_act for decode.
// ---------------------------------------------------------------------------
__global__ __launch_bounds__(256) void scatter_exact(
    const int* __restrict__ idxlist, const float* __restrict__ x,
    const float* __restrict__ W_enc, const float* __restrict__ benc2,
    float* __restrict__ enc, float* __restrict__ sel_act)
{
    int row = blockIdx.x;
    int b = row / NW_, w = row % NW_;
    int t0g = b * T_ + w * WIN_;
    __shared__ float xs[WIN_][C_];   // 32 KB
    __shared__ int sidx[K_];
    int tid = threadIdx.x;
    if (tid < K_) sidx[tid] = idxlist[(size_t)row * K_ + tid];
    for (int i = tid; i < WIN_ * C_; i += 256) xs[i >> 10][i & (C_ - 1)] = x[(size_t)t0g * C_ + i];
    __syncthreads();

    int hw = tid >> 5, ln = tid & 31;
    for (int ci = hw; ci < K_; ci += 8) {
        int d = sidx[ci];
        const float* wrow = W_enc + (size_t)d * C_;
        float a[WIN_] = {0.f, 0.f, 0.f, 0.f, 0.f, 0.f, 0.f, 0.f};
        for (int c = ln; c < C_; c += 32) {
            float wc = wrow[c];
            #pragma unroll
            for (int j = 0; j < WIN_; j++) a[j] = fmaf(wc, xs[j][c], a[j]);
        }
        #pragma unroll
        for (int off = 1; off < 32; off <<= 1)
            #pragma unroll
            for (int j = 0; j < WIN_; j++) a[j] += __shfl_xor(a[j], off);
        if (ln < WIN_) {
            float v = 0.f;
            #pragma unroll
            for (int j = 0; j < WIN_; j++) v = (ln == j) ? a[j] : v;  // static idx only
            v += benc2[d];
            v = v > 0.f ? v : 0.f;
            enc[(size_t)(t0g + ln) * D_ + d] = v;
            sel_act[((size_t)row * K_ + ci) * WIN_ + ln] = v;
        }
    }
}

// ---------------------------------------------------------------------------
// K7: sparse decode per window from compact sel_act
// ---------------------------------------------------------------------------
__global__ __launch_bounds__(256) void decode_win(
    const float* __restrict__ sel_act,
    const int* __restrict__ idxlist,
    const float* __restrict__ WdT,    // (D_, C_)
    const float* __restrict__ b_dec,
    float* __restrict__ recon)        // (M_, C_)
{
    int row = blockIdx.x;
    int b = row / NW_, w = row % NW_;
    int t0 = b * T_ + w * WIN_;
    __shared__ int sidx[K_];
    __shared__ float act[K_][WIN_];
    int tid = threadIdx.x;
    if (tid < K_) sidx[tid] = idxlist[(size_t)row * K_ + tid];
    for (int i = tid; i < K_ * WIN_; i += 256)
        ((float*)act)[i] = sel_act[(size_t)row * K_ * WIN_ + i];
    __syncthreads();

    float accv[WIN_][4] = {};
    int c0 = tid * 4;
    for (int i = 0; i < K_; ++i) {
        int d = sidx[i];
        float4 wv = *(const float4*)(WdT + (size_t)d * C_ + c0);
        float4 a03 = *(const float4*)(&act[i][0]);
        float4 a47 = *(const float4*)(&act[i][4]);
        float aj[8] = {a03.x, a03.y, a03.z, a03.w, a47.x, a47.y, a47.z, a47.w};
        #pragma unroll
        for (int j = 0; j < WIN_; j++) {
            accv[j][0] = fmaf(aj[j], wv.x, accv[j][0]);
            accv[j][1] = fmaf(aj[j], wv.y, accv[j][1]);
            accv[j][2] = fmaf(aj[j], wv.z, accv[j][2]);
            accv[j][3] = fmaf(aj[j], wv.w, accv[j][3]);
        }
    }
    float4 bd = *(const float4*)(b_dec + c0);
    #pragma unroll
    for (int j = 0; j < WIN_; j++) {
        float4 o;
        o.x = accv[j][0] + bd.x; o.y = accv[j][1] + bd.y;
        o.z = accv[j][2] + bd.z; o.w = accv[j][3] + bd.w;
        *(float4*)(recon + (size_t)(t0 + j) * C_ + c0) = o;
    }
}

// ---------------------------------------------------------------------------
extern "C" void kernel_launch(void* const* d_in, const int* in_sizes, int n_in,
                              void* d_out, int out_size, void* d_ws, size_t ws_size,
                              hipStream_t stream)
{
    const float* x     = (const float*)d_in[0];
    const float* W_enc = (const float*)d_in[1];
    const float* b_enc = (const float*)d_in[2];
    const float* W_dec = (const float*)d_in[3];
    const float* b_dec = (const float*)d_in[4];

    float* out   = (float*)d_out;
    float* recon = out;                        // M_*C_ floats
    float* enc   = out + (size_t)M_ * C_;      // M_*D_ floats (encoded output)

    // --- scratch with lifetime ending before the enc memset lives IN enc ---
    unsigned short* xbf    = (unsigned short*)enc;                 // 16.8 MB
    unsigned short* wencbf = xbf + (size_t)M_ * C_;                //  8.4 MB
    float*          wsums  = (float*)(wencbf + (size_t)D_ * C_);   // 16.8 MB

    // --- persistent scratch in d_ws (~22.3 MB) ---
    char* ws = (char*)d_ws;
    float*    WdT     = (float*)ws;                                         // 16.8 MB
    unsigned* bmask   = (unsigned*)(ws + (size_t)D_ * C_ * 4);              // 512 KB
    int*      idxlist = (int*)((char*)bmask + (size_t)(B_ * NW_) * (D_ / 32) * 4);  // 512 KB
    float*    benc2   = (float*)((char*)idxlist + (size_t)(B_ * NW_) * K_ * 4);     // 16 KB
    float*    sel_act = (float*)((char*)benc2 + D_ * 4);                    // 4 MB

    prep_benc<<<D_, 256, 0, stream>>>(W_enc, b_enc, b_dec, benc2);
    cvt_bf16<<<(M_ * C_ / 8 + 255) / 256, 256, 0, stream>>>(x, xbf, M_ * C_ / 8);
    cvt_bf16<<<(D_ * C_ / 8 + 255) / 256, 256, 0, stream>>>(W_enc, wencbf, D_ * C_ / 8);
    transpose_wdec<<<dim3(D_ / 32, C_ / 32), dim3(32, 8), 0, stream>>>(W_dec, WdT);
    mfma_gemm_ws<<<dim3(D_ / 128, M_ / 128), 256, 0, stream>>>(xbf, wencbf, benc2, wsums);
    fixup_ws<<<B_ * NW_, 256, 0, stream>>>(wsums, x, W_enc, benc2);
    topk_select<<<B_ * NW_, 256, 0, stream>>>(wsums, bmask, idxlist);
    hipMemsetAsync(enc, 0, (size_t)M_ * D_ * 4, stream);
    scatter_exact<<<B_ * NW_, 256, 0, stream>>>(idxlist, x, W_enc, benc2, enc, sel_act);
    decode_win<<<B_ * NW_, 256, 0, stream>>>(sel_act, idxlist, WdT, b_dec, recon);
}

// Round 3
// 315.773 us; speedup vs baseline: 3.0004x; 1.8631x over previous
//
#include <hip/hip_runtime.h>

#define B_   16
#define T_   512
#define C_   1024
#define D_   4096
#define K_   128
#define WIN_ 8
#define NW_  (T_ / WIN_)   // 64
#define M_   (B_ * T_)     // 8192

typedef __attribute__((ext_vector_type(8))) short bf16x8_t;
typedef __attribute__((ext_vector_type(4))) float f32x4_t;

__device__ __forceinline__ void gload16(const void* g, void* l) {
    __builtin_amdgcn_global_load_lds(
        (const __attribute__((address_space(1))) void*)g,
        (__attribute__((address_space(3))) void*)l, 16, 0, 0);
}

__device__ __forceinline__ unsigned short f2bf(float f) {
    unsigned u = __float_as_uint(f);
    unsigned r = (u + 0x7fffu + ((u >> 16) & 1u)) >> 16;
    return (unsigned short)r;
}

__device__ __forceinline__ unsigned f2key(float f) {
    unsigned u = __float_as_uint(f);
    return (u & 0x80000000u) ? ~u : (u | 0x80000000u);
}
__device__ __forceinline__ float key2f(unsigned k) {
    unsigned u = (k & 0x80000000u) ? (k & 0x7fffffffu) : ~k;
    return __uint_as_float(u);
}

// ---------------------------------------------------------------------------
// K0: benc2[d] = b_enc[d] - sum_c b_dec[c]*W_enc[d,c]
// ---------------------------------------------------------------------------
__global__ __launch_bounds__(256) void prep_benc(
    const float* __restrict__ W_enc, const float* __restrict__ b_enc,
    const float* __restrict__ b_dec, float* __restrict__ benc2)
{
    int d = blockIdx.x;
    const float* row = W_enc + (size_t)d * C_;
    float s = 0.f;
    for (int c = threadIdx.x; c < C_; c += 256) s += row[c] * b_dec[c];
    __shared__ float red[256];
    red[threadIdx.x] = s;
    __syncthreads();
    for (int off = 128; off > 0; off >>= 1) {
        if (threadIdx.x < off) red[threadIdx.x] += red[threadIdx.x + off];
        __syncthreads();
    }
    if (threadIdx.x == 0) benc2[d] = b_enc[d] - red[0];
}

// ---------------------------------------------------------------------------
// K1: fp32 -> bf16 (8 elems/thread)
// ---------------------------------------------------------------------------
__global__ void cvt_bf16(const float* __restrict__ in, unsigned short* __restrict__ out, int n8)
{
    int i = blockIdx.x * blockDim.x + threadIdx.x;
    if (i >= n8) return;
    const float4* p = (const float4*)(in + (size_t)i * 8);
    float4 a = p[0], b = p[1];
    uint4 o;
    o.x = (unsigned)f2bf(a.x) | ((unsigned)f2bf(a.y) << 16);
    o.y = (unsigned)f2bf(a.z) | ((unsigned)f2bf(a.w) << 16);
    o.z = (unsigned)f2bf(b.x) | ((unsigned)f2bf(b.y) << 16);
    o.w = (unsigned)f2bf(b.z) | ((unsigned)f2bf(b.w) << 16);
    ((uint4*)out)[i] = o;
}

// ---------------------------------------------------------------------------
// K2: transpose W_dec (C,D) -> WdT (D,C)
// ---------------------------------------------------------------------------
__global__ void transpose_wdec(const float* __restrict__ W, float* __restrict__ WT)
{
    __shared__ float tile[32][33];
    int d0 = blockIdx.x * 32;
    int c0 = blockIdx.y * 32;
    int tx = threadIdx.x, ty = threadIdx.y;  // (32,8)
    #pragma unroll
    for (int i = 0; i < 32; i += 8)
        tile[ty + i][tx] = W[(size_t)(c0 + ty + i) * D_ + d0 + tx];
    __syncthreads();
    #pragma unroll
    for (int i = 0; i < 32; i += 8)
        WT[(size_t)(d0 + ty + i) * C_ + c0 + tx] = tile[tx][ty + i];
}

// ---------------------------------------------------------------------------
// K3: bf16 MFMA GEMM. Epilogue stores DENSE relu'd activations (fp32) and
//     window sums. Staging/fragment logic identical to the round-2 kernel
//     (passed); adds: dense store + XCD-aware block swizzle.
// ---------------------------------------------------------------------------
__global__ __launch_bounds__(256) void mfma_gemm_dense(
    const unsigned short* __restrict__ Abf,  // x bf16 (M_, C_)
    const unsigned short* __restrict__ Bbf,  // W_enc bf16 (D_, C_)
    const float* __restrict__ benc2,
    float* __restrict__ enc,                 // (M_, D_) dense activations
    float* __restrict__ wsums)               // (B_*NW_, D_)
{
    __shared__ unsigned short lA[128 * 32];
    __shared__ unsigned short lB[128 * 32];
    int tid = threadIdx.x;
    int lane = tid & 63;
    int wv = tid >> 6;
    int wm = wv >> 1, wn = wv & 1;

    // XCD-aware swizzle: 2048 blocks, 8 XCDs, bijective chunked remap
    int lid = blockIdx.y * gridDim.x + blockIdx.x;
    int sw = (lid & 7) * 256 + (lid >> 3);
    int bn = sw & 31, bm = sw >> 5;

    f32x4_t acc[4][4];
    #pragma unroll
    for (int i = 0; i < 4; i++)
        #pragma unroll
        for (int j = 0; j < 4; j++) acc[i][j] = (f32x4_t){0.f, 0.f, 0.f, 0.f};

    const unsigned short* Ab = Abf + (size_t)bm * 128 * C_;
    const unsigned short* Bb = Bbf + (size_t)bn * 128 * C_;

    int m_s[2], u_s[2];
    #pragma unroll
    for (int q = 0; q < 2; q++) {
        int p = q * 256 + tid;
        int m = p >> 2, v = p & 3;
        m_s[q] = m;
        u_s[q] = v ^ ((m >> 1) & 3);
    }

    int r = lane & 15, g = lane >> 4;
    for (int k0 = 0; k0 < C_; k0 += 32) {
        __syncthreads();
        #pragma unroll
        for (int q = 0; q < 2; q++) {
            gload16(Ab + (size_t)m_s[q] * C_ + k0 + u_s[q] * 8,
                    &lA[(q * 256 + wv * 64) * 8]);
            gload16(Bb + (size_t)m_s[q] * C_ + k0 + u_s[q] * 8,
                    &lB[(q * 256 + wv * 64) * 8]);
        }
        __syncthreads();
        bf16x8_t af[4], bfr[4];
        #pragma unroll
        for (int mi = 0; mi < 4; mi++) {
            int m = wm * 64 + mi * 16 + r;
            int u = g ^ ((m >> 1) & 3);
            af[mi] = *(const bf16x8_t*)&lA[m * 32 + u * 8];
        }
        #pragma unroll
        for (int ni = 0; ni < 4; ni++) {
            int d = wn * 64 + ni * 16 + r;
            int u = g ^ ((d >> 1) & 3);
            bfr[ni] = *(const bf16x8_t*)&lB[d * 32 + u * 8];
        }
        #pragma unroll
        for (int mi = 0; mi < 4; mi++)
            #pragma unroll
            for (int ni = 0; ni < 4; ni++)
                acc[mi][ni] = __builtin_amdgcn_mfma_f32_16x16x32_bf16(
                    af[mi], bfr[ni], acc[mi][ni], 0, 0, 0);
    }

    // epilogue: C/D layout col=lane&15, row=(lane>>4)*4+reg
    int b = bm >> 2;
    int t_blk = (bm & 3) * 128;
    #pragma unroll
    for (int ni = 0; ni < 4; ni++) {
        int d = bn * 128 + wn * 64 + ni * 16 + r;
        float bias = benc2[d];
        #pragma unroll
        for (int mi = 0; mi < 4; mi++) {
            int mbase = bm * 128 + wm * 64 + mi * 16 + g * 4;  // global row of q=0
            float s = 0.f;
            #pragma unroll
            for (int q = 0; q < 4; q++) {
                float v = acc[mi][ni][q] + bias;
                v = v > 0.f ? v : 0.f;
                enc[(size_t)(mbase + q) * D_ + d] = v;
                s += v;
            }
            float partner = __shfl_xor(s, 16);   // pair lane-groups (0,1),(2,3)
            float wsv = s + partner;
            int t0 = t_blk + wm * 64 + mi * 16;
            int wrow = b * NW_ + (t0 >> 3) + (g >> 1);
            if ((g & 1) == 0)
                wsums[(size_t)wrow * D_ + d] = wsv;
        }
    }
}

// ---------------------------------------------------------------------------
// K4: fp32 fixup of window-sums near the top-K boundary.
//   Radix-select approx kth (parallel suffix-scan bucket find), recompute
//   exactly every |ws-kth|<=DELTA entry with one 64-lane wave per row.
// ---------------------------------------------------------------------------
#define DELTA 0.15f
#define MAXCAND 320

__global__ __launch_bounds__(256) void fixup_ws(
    float* __restrict__ wsums, const float* __restrict__ x,
    const float* __restrict__ W_enc, const float* __restrict__ benc2)
{
    int row = blockIdx.x;             // b*NW + w
    int b = row / NW_, w = row % NW_;
    int t0g = b * T_ + w * WIN_;
    __shared__ float wsh[D_];         // 16 KB
    __shared__ float xs[WIN_][C_];    // 32 KB
    __shared__ int hist[256];
    __shared__ int scan[256];
    __shared__ unsigned sh_prefix;
    __shared__ int sh_need;
    __shared__ int cand[MAXCAND];
    __shared__ int ncand;
    int tid = threadIdx.x;

    for (int i = tid; i < D_ / 4; i += 256)
        ((float4*)wsh)[i] = ((const float4*)(wsums + (size_t)row * D_))[i];
    for (int i = tid; i < WIN_ * C_ / 4; i += 256)
        ((float4*)xs)[i] = ((const float4*)(x + (size_t)t0g * C_))[i];
    if (tid == 0) { sh_prefix = 0u; sh_need = K_; ncand = 0; }
    __syncthreads();

    for (int pass = 0; pass < 4; ++pass) {
        int shift = 24 - pass * 8;
        unsigned pref = sh_prefix;
        unsigned pmask = (pass == 0) ? 0u : (0xFFFFFFFFu << (shift + 8));
        hist[tid] = 0;
        __syncthreads();
        for (int i = tid; i < D_; i += 256) {
            unsigned k = f2key(wsh[i]);
            if ((k & pmask) == pref)
                atomicAdd(&hist[(k >> shift) & 0xFF], 1);
        }
        __syncthreads();
        // parallel suffix-sum bucket find
        scan[tid] = hist[tid];
        __syncthreads();
        for (int off = 1; off < 256; off <<= 1) {
            int t = (tid + off < 256) ? scan[tid + off] : 0;
            __syncthreads();
            scan[tid] += t;
            __syncthreads();
        }
        int need = sh_need;
        int snext = (tid < 255) ? scan[tid + 1] : 0;
        if (scan[tid] >= need && snext < need) {
            sh_prefix = pref | ((unsigned)tid << shift);
            sh_need = need - snext;
        }
        __syncthreads();
    }
    float kthf = key2f(sh_prefix);

    for (int i = tid; i < D_; i += 256) {
        if (fabsf(wsh[i] - kthf) <= DELTA) {
            int pos = atomicAdd(&ncand, 1);
            if (pos < MAXCAND) cand[pos] = i;
        }
    }
    __syncthreads();
    int nc = ncand < MAXCAND ? ncand : MAXCAND;

    // one 64-lane wave per candidate row; float4 everywhere
    int wvi = tid >> 6, ln = tid & 63;
    int c0 = ln * 4;
    for (int cb = wvi; cb < nc; cb += 4) {
        int d = cand[cb];
        const float* wrow = W_enc + (size_t)d * C_;
        float a[WIN_] = {0.f, 0.f, 0.f, 0.f, 0.f, 0.f, 0.f, 0.f};
        #pragma unroll
        for (int q = 0; q < 4; q++) {
            float4 wq = *(const float4*)(wrow + q * 256 + c0);
            #pragma unroll
            for (int j = 0; j < WIN_; j++) {
                float4 xq = *(const float4*)(&xs[j][q * 256 + c0]);
                a[j] = fmaf(wq.x, xq.x, a[j]);
                a[j] = fmaf(wq.y, xq.y, a[j]);
                a[j] = fmaf(wq.z, xq.z, a[j]);
                a[j] = fmaf(wq.w, xq.w, a[j]);
            }
        }
        #pragma unroll
        for (int off = 1; off < 64; off <<= 1)
            #pragma unroll
            for (int j = 0; j < WIN_; j++) a[j] += __shfl_xor(a[j], off);
        if (ln == 0) {
            float bias = benc2[d], s = 0.f;
            #pragma unroll
            for (int j = 0; j < WIN_; j++) {
                float v = a[j] + bias;
                s += v > 0.f ? v : 0.f;
            }
            wsums[(size_t)row * D_ + d] = s;
        }
    }
}

// ---------------------------------------------------------------------------
// K5: exact top-K=128 radix select (parallel bucket find; tie-break = lowest idx)
// ---------------------------------------------------------------------------
__global__ __launch_bounds__(256) void topk_select(
    const float* __restrict__ wsums,
    unsigned* __restrict__ bmask,
    int* __restrict__ idxlist)
{
    int row = blockIdx.x;
    __shared__ unsigned keys[D_];
    __shared__ int hist[256];
    __shared__ int scan[256];
    __shared__ unsigned short hbits[256];
    __shared__ unsigned sh_prefix;
    __shared__ int sh_need;
    int tid = threadIdx.x;

    for (int i = tid; i < D_ / 4; i += 256) {
        float4 v = ((const float4*)(wsums + (size_t)row * D_))[i];
        keys[i * 4 + 0] = f2key(v.x);
        keys[i * 4 + 1] = f2key(v.y);
        keys[i * 4 + 2] = f2key(v.z);
        keys[i * 4 + 3] = f2key(v.w);
    }
    if (tid == 0) { sh_prefix = 0u; sh_need = K_; }
    __syncthreads();

    for (int pass = 0; pass < 4; ++pass) {
        int shift = 24 - pass * 8;
        unsigned pref = sh_prefix;
        unsigned pmask = (pass == 0) ? 0u : (0xFFFFFFFFu << (shift + 8));
        hist[tid] = 0;
        __syncthreads();
        for (int i = tid; i < D_; i += 256) {
            unsigned k = keys[i];
            if ((k & pmask) == pref)
                atomicAdd(&hist[(k >> shift) & 0xFF], 1);
        }
        __syncthreads();
        scan[tid] = hist[tid];
        __syncthreads();
        for (int off = 1; off < 256; off <<= 1) {
            int t = (tid + off < 256) ? scan[tid + off] : 0;
            __syncthreads();
            scan[tid] += t;
            __syncthreads();
        }
        int need = sh_need;
        int snext = (tid < 255) ? scan[tid + 1] : 0;
        if (scan[tid] >= need && snext < need) {
            sh_prefix = pref | ((unsigned)tid << shift);
            sh_need = need - snext;
        }
        __syncthreads();
    }
    unsigned kth = sh_prefix;
    int need_eq = sh_need;

    int base = tid * 16;
    unsigned mybits = 0;
    int eqcnt = 0;
    #pragma unroll
    for (int j = 0; j < 16; ++j) {
        unsigned k = keys[base + j];
        if (k > kth) mybits |= (1u << j);
        else if (k == kth) eqcnt++;
    }
    scan[tid] = eqcnt;
    __syncthreads();
    for (int off = 1; off < 256; off <<= 1) {
        int t = (tid >= off) ? scan[tid - off] : 0;
        __syncthreads();
        scan[tid] += t;
        __syncthreads();
    }
    int rr = scan[tid] - eqcnt;
    #pragma unroll
    for (int j = 0; j < 16; ++j) {
        unsigned k = keys[base + j];
        if (k == kth) { if (rr < need_eq) mybits |= (1u << j); rr++; }
    }
    hbits[tid] = (unsigned short)mybits;
    __syncthreads();
    if (tid < D_ / 32)
        bmask[(size_t)row * (D_ / 32) + tid] =
            (unsigned)hbits[2 * tid] | ((unsigned)hbits[2 * tid + 1] << 16);

    int selcnt = __popc(mybits);
    __syncthreads();
    scan[tid] = selcnt;
    __syncthreads();
    for (int off = 1; off < 256; off <<= 1) {
        int t = (tid >= off) ? scan[tid - off] : 0;
        __syncthreads();
        scan[tid] += t;
        __syncthreads();
    }
    int pos = scan[tid] - selcnt;
    #pragma unroll
    for (int j = 0; j < 16; ++j) {
        if (mybits & (1u << j)) idxlist[(size_t)row * K_ + pos++] = base + j;
    }
}

// ---------------------------------------------------------------------------
// K6: zero non-selected entries of dense enc in place
// ---------------------------------------------------------------------------
__global__ void apply_mask(float* __restrict__ enc, const unsigned* __restrict__ bmask)
{
    size_t idx = ((size_t)blockIdx.x * blockDim.x + threadIdx.x) * 4;
    size_t m = idx >> 12;             // / D_
    int d = (int)(idx & (D_ - 1));
    int b = (int)(m / T_);
    int t = (int)(m % T_);
    int wrow = b * NW_ + (t >> 3);
    unsigned word = bmask[(size_t)wrow * (D_ / 32) + (d >> 5)];
    int sh = d & 31;
    float4 v = *(float4*)(enc + idx);
    v.x = ((word >> (sh + 0)) & 1u) ? v.x : 0.f;
    v.y = ((word >> (sh + 1)) & 1u) ? v.y : 0.f;
    v.z = ((word >> (sh + 2)) & 1u) ? v.z : 0.f;
    v.w = ((word >> (sh + 3)) & 1u) ? v.w : 0.f;
    *(float4*)(enc + idx) = v;
}

// ---------------------------------------------------------------------------
// K7: sparse decode per window, gathering activations from masked enc
// ---------------------------------------------------------------------------
__global__ __launch_bounds__(256) void decode_win(
    const float* __restrict__ enc,
    const int* __restrict__ idxlist,
    const float* __restrict__ WdT,    // (D_, C_)
    const float* __restrict__ b_dec,
    float* __restrict__ recon)        // (M_, C_)
{
    int row = blockIdx.x;
    int b = row / NW_, w = row % NW_;
    int t0 = b * T_ + w * WIN_;
    __shared__ int sidx[K_];
    __shared__ float act[K_][WIN_];
    int tid = threadIdx.x;
    if (tid < K_) sidx[tid] = idxlist[(size_t)row * K_ + tid];
    __syncthreads();
    if (tid < K_) {
        int d = sidx[tid];
        #pragma unroll
        for (int j = 0; j < WIN_; j++)
            act[tid][j] = enc[(size_t)(t0 + j) * D_ + d];
    }
    __syncthreads();

    float accv[WIN_][4] = {};
    int c0 = tid * 4;
    for (int i = 0; i < K_; ++i) {
        int d = sidx[i];
        float4 wv = *(const float4*)(WdT + (size_t)d * C_ + c0);
        float4 a03 = *(const float4*)(&act[i][0]);
        float4 a47 = *(const float4*)(&act[i][4]);
        float aj[8] = {a03.x, a03.y, a03.z, a03.w, a47.x, a47.y, a47.z, a47.w};
        #pragma unroll
        for (int j = 0; j < WIN_; j++) {
            accv[j][0] = fmaf(aj[j], wv.x, accv[j][0]);
            accv[j][1] = fmaf(aj[j], wv.y, accv[j][1]);
            accv[j][2] = fmaf(aj[j], wv.z, accv[j][2]);
            accv[j][3] = fmaf(aj[j], wv.w, accv[j][3]);
        }
    }
    float4 bd = *(const float4*)(b_dec + c0);
    #pragma unroll
    for (int j = 0; j < WIN_; j++) {
        float4 o;
        o.x = accv[j][0] + bd.x; o.y = accv[j][1] + bd.y;
        o.z = accv[j][2] + bd.z; o.w = accv[j][3] + bd.w;
        *(float4*)(recon + (size_t)(t0 + j) * C_ + c0) = o;
    }
}

// ---------------------------------------------------------------------------
extern "C" void kernel_launch(void* const* d_in, const int* in_sizes, int n_in,
                              void* d_out, int out_size, void* d_ws, size_t ws_size,
                              hipStream_t stream)
{
    const float* x     = (const float*)d_in[0];
    const float* W_enc = (const float*)d_in[1];
    const float* b_enc = (const float*)d_in[2];
    const float* W_dec = (const float*)d_in[3];
    const float* b_dec = (const float*)d_in[4];

    float* out   = (float*)d_out;
    float* recon = out;                        // M_*C_ floats
    float* enc   = out + (size_t)M_ * C_;      // M_*D_ floats (dense -> masked)

    // scratch inside recon region (dead before decode writes recon):
    //   xbf   : 16.8 MB  (bf16 x)
    //   wsums : 16.8 MB  (window sums)  -- exactly fills recon (33.55 MB)
    unsigned short* xbf   = (unsigned short*)recon;
    float*          wsums = (float*)((char*)recon + (size_t)M_ * C_ * 2);

    // persistent scratch in d_ws (~26.2 MB)
    char* ws = (char*)d_ws;
    float*          WdT     = (float*)ws;                                   // 16.8 MB
    unsigned*       bmask   = (unsigned*)(ws + (size_t)D_ * C_ * 4);        // 512 KB
    int*            idxlist = (int*)((char*)bmask + (size_t)(B_ * NW_) * (D_ / 32) * 4);
    float*          benc2   = (float*)((char*)idxlist + (size_t)(B_ * NW_) * K_ * 4);
    unsigned short* wencbf  = (unsigned short*)((char*)benc2 + D_ * 4);     // 8.4 MB

    prep_benc<<<D_, 256, 0, stream>>>(W_enc, b_enc, b_dec, benc2);
    cvt_bf16<<<(M_ * C_ / 8 + 255) / 256, 256, 0, stream>>>(x, xbf, M_ * C_ / 8);
    cvt_bf16<<<(D_ * C_ / 8 + 255) / 256, 256, 0, stream>>>(W_enc, wencbf, D_ * C_ / 8);
    transpose_wdec<<<dim3(D_ / 32, C_ / 32), dim3(32, 8), 0, stream>>>(W_dec, WdT);
    mfma_gemm_dense<<<dim3(32, 64), 256, 0, stream>>>(xbf, wencbf, benc2, enc, wsums);
    fixup_ws<<<B_ * NW_, 256, 0, stream>>>(wsums, x, W_enc, benc2);
    topk_select<<<B_ * NW_, 256, 0, stream>>>(wsums, bmask, idxlist);
    apply_mask<<<(int)((size_t)M_ * D_ / 4 / 256), 256, 0, stream>>>(enc, bmask);
    decode_win<<<B_ * NW_, 256, 0, stream>>>(enc, idxlist, WdT, b_dec, recon);
}

// Round 4
// 303.165 us; speedup vs baseline: 3.1251x; 1.0416x over previous
//
#include <hip/hip_runtime.h>

#define B_   16
#define T_   512
#define C_   1024
#define D_   4096
#define K_   128
#define WIN_ 8
#define NW_  (T_ / WIN_)   // 64
#define M_   (B_ * T_)     // 8192

typedef __attribute__((ext_vector_type(8))) short bf16x8_t;
typedef __attribute__((ext_vector_type(4))) float f32x4_t;

__device__ __forceinline__ void gload16(const void* g, void* l) {
    __builtin_amdgcn_global_load_lds(
        (const __attribute__((address_space(1))) void*)g,
        (__attribute__((address_space(3))) void*)l, 16, 0, 0);
}

__device__ __forceinline__ unsigned short f2bf(float f) {
    unsigned u = __float_as_uint(f);
    unsigned r = (u + 0x7fffu + ((u >> 16) & 1u)) >> 16;
    return (unsigned short)r;
}

__device__ __forceinline__ unsigned f2key(float f) {
    unsigned u = __float_as_uint(f);
    return (u & 0x80000000u) ? ~u : (u | 0x80000000u);
}
__device__ __forceinline__ float key2f(unsigned k) {
    unsigned u = (k & 0x80000000u) ? (k & 0x7fffffffu) : ~k;
    return __uint_as_float(u);
}

// ---------------------------------------------------------------------------
// K0: benc2[d] = b_enc[d] - sum_c b_dec[c]*W_enc[d,c]
// ---------------------------------------------------------------------------
__global__ __launch_bounds__(256) void prep_benc(
    const float* __restrict__ W_enc, const float* __restrict__ b_enc,
    const float* __restrict__ b_dec, float* __restrict__ benc2)
{
    int d = blockIdx.x;
    const float* row = W_enc + (size_t)d * C_;
    float s = 0.f;
    for (int c = threadIdx.x; c < C_; c += 256) s += row[c] * b_dec[c];
    __shared__ float red[256];
    red[threadIdx.x] = s;
    __syncthreads();
    for (int off = 128; off > 0; off >>= 1) {
        if (threadIdx.x < off) red[threadIdx.x] += red[threadIdx.x + off];
        __syncthreads();
    }
    if (threadIdx.x == 0) benc2[d] = b_enc[d] - red[0];
}

// ---------------------------------------------------------------------------
// K1: fp32 -> bf16 (8 elems/thread)
// ---------------------------------------------------------------------------
__global__ void cvt_bf16(const float* __restrict__ in, unsigned short* __restrict__ out, int n8)
{
    int i = blockIdx.x * blockDim.x + threadIdx.x;
    if (i >= n8) return;
    const float4* p = (const float4*)(in + (size_t)i * 8);
    float4 a = p[0], b = p[1];
    uint4 o;
    o.x = (unsigned)f2bf(a.x) | ((unsigned)f2bf(a.y) << 16);
    o.y = (unsigned)f2bf(a.z) | ((unsigned)f2bf(a.w) << 16);
    o.z = (unsigned)f2bf(b.x) | ((unsigned)f2bf(b.y) << 16);
    o.w = (unsigned)f2bf(b.z) | ((unsigned)f2bf(b.w) << 16);
    ((uint4*)out)[i] = o;
}

// ---------------------------------------------------------------------------
// K2: transpose W_dec (C,D) -> WdT (D,C)
// ---------------------------------------------------------------------------
__global__ void transpose_wdec(const float* __restrict__ W, float* __restrict__ WT)
{
    __shared__ float tile[32][33];
    int d0 = blockIdx.x * 32;
    int c0 = blockIdx.y * 32;
    int tx = threadIdx.x, ty = threadIdx.y;  // (32,8)
    #pragma unroll
    for (int i = 0; i < 32; i += 8)
        tile[ty + i][tx] = W[(size_t)(c0 + ty + i) * D_ + d0 + tx];
    __syncthreads();
    #pragma unroll
    for (int i = 0; i < 32; i += 8)
        WT[(size_t)(d0 + ty + i) * C_ + c0 + tx] = tile[tx][ty + i];
}

// ---------------------------------------------------------------------------
// K3: bf16 MFMA GEMM. K-loop identical to round-3 (proven). Epilogue now
//     stages both the dense activations and the window sums through
//     wave-private LDS slabs so all global stores are float4-coalesced
//     (256B/128B segments instead of 64B scalar segments).
// ---------------------------------------------------------------------------
__global__ __launch_bounds__(256) void mfma_gemm_dense(
    const unsigned short* __restrict__ Abf,  // x bf16 (M_, C_)
    const unsigned short* __restrict__ Bbf,  // W_enc bf16 (D_, C_)
    const float* __restrict__ benc2,
    float* __restrict__ enc,                 // (M_, D_) dense activations
    float* __restrict__ wsums)               // (B_*NW_, D_)
{
    __shared__ unsigned short lA[128 * 32];
    __shared__ unsigned short lB[128 * 32];
    __shared__ float cst[4][16][68];         // wave-private C-stage (17 KB)
    int tid = threadIdx.x;
    int lane = tid & 63;
    int wv = tid >> 6;
    int wm = wv >> 1, wn = wv & 1;

    // XCD-aware swizzle: 2048 blocks, 8 XCDs, bijective chunked remap
    int lid = blockIdx.y * gridDim.x + blockIdx.x;
    int sw = (lid & 7) * 256 + (lid >> 3);
    int bn = sw & 31, bm = sw >> 5;

    f32x4_t acc[4][4];
    #pragma unroll
    for (int i = 0; i < 4; i++)
        #pragma unroll
        for (int j = 0; j < 4; j++) acc[i][j] = (f32x4_t){0.f, 0.f, 0.f, 0.f};

    const unsigned short* Ab = Abf + (size_t)bm * 128 * C_;
    const unsigned short* Bb = Bbf + (size_t)bn * 128 * C_;

    int m_s[2], u_s[2];
    #pragma unroll
    for (int q = 0; q < 2; q++) {
        int p = q * 256 + tid;
        int m = p >> 2, v = p & 3;
        m_s[q] = m;
        u_s[q] = v ^ ((m >> 1) & 3);
    }

    int r = lane & 15, g = lane >> 4;
    for (int k0 = 0; k0 < C_; k0 += 32) {
        __syncthreads();
        #pragma unroll
        for (int q = 0; q < 2; q++) {
            gload16(Ab + (size_t)m_s[q] * C_ + k0 + u_s[q] * 8,
                    &lA[(q * 256 + wv * 64) * 8]);
            gload16(Bb + (size_t)m_s[q] * C_ + k0 + u_s[q] * 8,
                    &lB[(q * 256 + wv * 64) * 8]);
        }
        __syncthreads();
        bf16x8_t af[4], bfr[4];
        #pragma unroll
        for (int mi = 0; mi < 4; mi++) {
            int m = wm * 64 + mi * 16 + r;
            int u = g ^ ((m >> 1) & 3);
            af[mi] = *(const bf16x8_t*)&lA[m * 32 + u * 8];
        }
        #pragma unroll
        for (int ni = 0; ni < 4; ni++) {
            int d = wn * 64 + ni * 16 + r;
            int u = g ^ ((d >> 1) & 3);
            bfr[ni] = *(const bf16x8_t*)&lB[d * 32 + u * 8];
        }
        #pragma unroll
        for (int mi = 0; mi < 4; mi++)
            #pragma unroll
            for (int ni = 0; ni < 4; ni++)
                acc[mi][ni] = __builtin_amdgcn_mfma_f32_16x16x32_bf16(
                    af[mi], bfr[ni], acc[mi][ni], 0, 0, 0);
    }

    // ---- epilogue (C/D layout: col=lane&15, row=(lane>>4)*4+reg) ----
    int b = bm >> 2;
    int t_blk = (bm & 3) * 128;
    int dbase = bn * 128 + wn * 64;
    int mbase_w = bm * 128 + wm * 64;                  // global row base of wave
    int wbase = b * NW_ + (t_blk >> 3) + wm * 8;       // window-row base of wave

    float bias_r[4];
    #pragma unroll
    for (int ni = 0; ni < 4; ni++) bias_r[ni] = benc2[dbase + ni * 16 + r];

    float wsv[4][4];   // per (mi,ni); valid on even-g lanes
    #pragma unroll
    for (int mi = 0; mi < 4; mi++) {
        #pragma unroll
        for (int ni = 0; ni < 4; ni++) {
            float s = 0.f;
            #pragma unroll
            for (int q = 0; q < 4; q++) {
                float v = acc[mi][ni][q] + bias_r[ni];
                v = v > 0.f ? v : 0.f;
                cst[wv][g * 4 + q][ni * 16 + r] = v;
                s += v;
            }
            float partner = __shfl_xor(s, 16);   // pair lane-groups (0,1),(2,3)
            wsv[mi][ni] = s + partner;
        }
        // same-wave LDS write->read: compiler inserts lgkmcnt, no barrier
        #pragma unroll
        for (int ri = 0; ri < 4; ri++) {
            int row = ri * 4 + (lane >> 4);
            int c4 = (lane & 15) * 4;
            float4 vv = *(const float4*)&cst[wv][row][c4];
            *(float4*)(enc + (size_t)(mbase_w + mi * 16 + row) * D_ + dbase + c4) = vv;
        }
    }

    // window sums: even-g lanes own (wrow = wbase + mi*2 + g/2, d = dbase+ni*16+r)
    if ((g & 1) == 0) {
        #pragma unroll
        for (int mi = 0; mi < 4; mi++)
            #pragma unroll
            for (int ni = 0; ni < 4; ni++)
                cst[wv][mi * 2 + (g >> 1)][ni * 16 + r] = wsv[mi][ni];
    }
    #pragma unroll
    for (int it = 0; it < 2; it++) {
        int row = lane >> 3;                 // 0..7
        int c4 = (lane & 7) * 4 + it * 32;
        float4 vv = *(const float4*)&cst[wv][row][c4];
        *(float4*)(wsums + (size_t)(wbase + row) * D_ + dbase + c4) = vv;
    }
}

// ---------------------------------------------------------------------------
// K4: fp32 fixup of window-sums near the top-K boundary.
// ---------------------------------------------------------------------------
#define DELTA 0.15f
#define MAXCAND 320

__global__ __launch_bounds__(256) void fixup_ws(
    float* __restrict__ wsums, const float* __restrict__ x,
    const float* __restrict__ W_enc, const float* __restrict__ benc2)
{
    int row = blockIdx.x;             // b*NW + w
    int b = row / NW_, w = row % NW_;
    int t0g = b * T_ + w * WIN_;
    __shared__ float wsh[D_];         // 16 KB
    __shared__ float xs[WIN_][C_];    // 32 KB
    __shared__ int hist[256];
    __shared__ int scan[256];
    __shared__ unsigned sh_prefix;
    __shared__ int sh_need;
    __shared__ int cand[MAXCAND];
    __shared__ int ncand;
    int tid = threadIdx.x;

    for (int i = tid; i < D_ / 4; i += 256)
        ((float4*)wsh)[i] = ((const float4*)(wsums + (size_t)row * D_))[i];
    for (int i = tid; i < WIN_ * C_ / 4; i += 256)
        ((float4*)xs)[i] = ((const float4*)(x + (size_t)t0g * C_))[i];
    if (tid == 0) { sh_prefix = 0u; sh_need = K_; ncand = 0; }
    __syncthreads();

    for (int pass = 0; pass < 4; ++pass) {
        int shift = 24 - pass * 8;
        unsigned pref = sh_prefix;
        unsigned pmask = (pass == 0) ? 0u : (0xFFFFFFFFu << (shift + 8));
        hist[tid] = 0;
        __syncthreads();
        for (int i = tid; i < D_; i += 256) {
            unsigned k = f2key(wsh[i]);
            if ((k & pmask) == pref)
                atomicAdd(&hist[(k >> shift) & 0xFF], 1);
        }
        __syncthreads();
        scan[tid] = hist[tid];
        __syncthreads();
        for (int off = 1; off < 256; off <<= 1) {
            int t = (tid + off < 256) ? scan[tid + off] : 0;
            __syncthreads();
            scan[tid] += t;
            __syncthreads();
        }
        int need = sh_need;
        int snext = (tid < 255) ? scan[tid + 1] : 0;
        if (scan[tid] >= need && snext < need) {
            sh_prefix = pref | ((unsigned)tid << shift);
            sh_need = need - snext;
        }
        __syncthreads();
    }
    float kthf = key2f(sh_prefix);

    for (int i = tid; i < D_; i += 256) {
        if (fabsf(wsh[i] - kthf) <= DELTA) {
            int pos = atomicAdd(&ncand, 1);
            if (pos < MAXCAND) cand[pos] = i;
        }
    }
    __syncthreads();
    int nc = ncand < MAXCAND ? ncand : MAXCAND;

    int wvi = tid >> 6, ln = tid & 63;
    int c0 = ln * 4;
    for (int cb = wvi; cb < nc; cb += 4) {
        int d = cand[cb];
        const float* wrow = W_enc + (size_t)d * C_;
        float a[WIN_] = {0.f, 0.f, 0.f, 0.f, 0.f, 0.f, 0.f, 0.f};
        #pragma unroll
        for (int q = 0; q < 4; q++) {
            float4 wq = *(const float4*)(wrow + q * 256 + c0);
            #pragma unroll
            for (int j = 0; j < WIN_; j++) {
                float4 xq = *(const float4*)(&xs[j][q * 256 + c0]);
                a[j] = fmaf(wq.x, xq.x, a[j]);
                a[j] = fmaf(wq.y, xq.y, a[j]);
                a[j] = fmaf(wq.z, xq.z, a[j]);
                a[j] = fmaf(wq.w, xq.w, a[j]);
            }
        }
        #pragma unroll
        for (int off = 1; off < 64; off <<= 1)
            #pragma unroll
            for (int j = 0; j < WIN_; j++) a[j] += __shfl_xor(a[j], off);
        if (ln == 0) {
            float bias = benc2[d], s = 0.f;
            #pragma unroll
            for (int j = 0; j < WIN_; j++) {
                float v = a[j] + bias;
                s += v > 0.f ? v : 0.f;
            }
            wsums[(size_t)row * D_ + d] = s;
        }
    }
}

// ---------------------------------------------------------------------------
// K5: exact top-K=128 radix select
// ---------------------------------------------------------------------------
__global__ __launch_bounds__(256) void topk_select(
    const float* __restrict__ wsums,
    unsigned* __restrict__ bmask,
    int* __restrict__ idxlist)
{
    int row = blockIdx.x;
    __shared__ unsigned keys[D_];
    __shared__ int hist[256];
    __shared__ int scan[256];
    __shared__ unsigned short hbits[256];
    __shared__ unsigned sh_prefix;
    __shared__ int sh_need;
    int tid = threadIdx.x;

    for (int i = tid; i < D_ / 4; i += 256) {
        float4 v = ((const float4*)(wsums + (size_t)row * D_))[i];
        keys[i * 4 + 0] = f2key(v.x);
        keys[i * 4 + 1] = f2key(v.y);
        keys[i * 4 + 2] = f2key(v.z);
        keys[i * 4 + 3] = f2key(v.w);
    }
    if (tid == 0) { sh_prefix = 0u; sh_need = K_; }
    __syncthreads();

    for (int pass = 0; pass < 4; ++pass) {
        int shift = 24 - pass * 8;
        unsigned pref = sh_prefix;
        unsigned pmask = (pass == 0) ? 0u : (0xFFFFFFFFu << (shift + 8));
        hist[tid] = 0;
        __syncthreads();
        for (int i = tid; i < D_; i += 256) {
            unsigned k = keys[i];
            if ((k & pmask) == pref)
                atomicAdd(&hist[(k >> shift) & 0xFF], 1);
        }
        __syncthreads();
        scan[tid] = hist[tid];
        __syncthreads();
        for (int off = 1; off < 256; off <<= 1) {
            int t = (tid + off < 256) ? scan[tid + off] : 0;
            __syncthreads();
            scan[tid] += t;
            __syncthreads();
        }
        int need = sh_need;
        int snext = (tid < 255) ? scan[tid + 1] : 0;
        if (scan[tid] >= need && snext < need) {
            sh_prefix = pref | ((unsigned)tid << shift);
            sh_need = need - snext;
        }
        __syncthreads();
    }
    unsigned kth = sh_prefix;
    int need_eq = sh_need;

    int base = tid * 16;
    unsigned mybits = 0;
    int eqcnt = 0;
    #pragma unroll
    for (int j = 0; j < 16; ++j) {
        unsigned k = keys[base + j];
        if (k > kth) mybits |= (1u << j);
        else if (k == kth) eqcnt++;
    }
    scan[tid] = eqcnt;
    __syncthreads();
    for (int off = 1; off < 256; off <<= 1) {
        int t = (tid >= off) ? scan[tid - off] : 0;
        __syncthreads();
        scan[tid] += t;
        __syncthreads();
    }
    int rr = scan[tid] - eqcnt;
    #pragma unroll
    for (int j = 0; j < 16; ++j) {
        unsigned k = keys[base + j];
        if (k == kth) { if (rr < need_eq) mybits |= (1u << j); rr++; }
    }
    hbits[tid] = (unsigned short)mybits;
    __syncthreads();
    if (tid < D_ / 32)
        bmask[(size_t)row * (D_ / 32) + tid] =
            (unsigned)hbits[2 * tid] | ((unsigned)hbits[2 * tid + 1] << 16);

    int selcnt = __popc(mybits);
    __syncthreads();
    scan[tid] = selcnt;
    __syncthreads();
    for (int off = 1; off < 256; off <<= 1) {
        int t = (tid >= off) ? scan[tid - off] : 0;
        __syncthreads();
        scan[tid] += t;
        __syncthreads();
    }
    int pos = scan[tid] - selcnt;
    #pragma unroll
    for (int j = 0; j < 16; ++j) {
        if (mybits & (1u << j)) idxlist[(size_t)row * K_ + pos++] = base + j;
    }
}

// ---------------------------------------------------------------------------
// K6: mask dense enc in place; zero-words write zeros WITHOUT reading enc
//     (97% of words are zero -> drops most of the fetch traffic)
// ---------------------------------------------------------------------------
__global__ void apply_mask(float* __restrict__ enc, const unsigned* __restrict__ bmask)
{
    size_t idx = ((size_t)blockIdx.x * blockDim.x + threadIdx.x) * 4;
    size_t m = idx >> 12;             // / D_
    int d = (int)(idx & (D_ - 1));
    int b = (int)(m / T_);
    int t = (int)(m % T_);
    int wrow = b * NW_ + (t >> 3);
    unsigned word = bmask[(size_t)wrow * (D_ / 32) + (d >> 5)];
    unsigned nib = (word >> (d & 31)) & 0xFu;   // idx is 4-aligned in d
    float4 v = {0.f, 0.f, 0.f, 0.f};
    if (nib) {
        v = *(float4*)(enc + idx);
        if (!(nib & 1u)) v.x = 0.f;
        if (!(nib & 2u)) v.y = 0.f;
        if (!(nib & 4u)) v.z = 0.f;
        if (!(nib & 8u)) v.w = 0.f;
    }
    *(float4*)(enc + idx) = v;
}

// ---------------------------------------------------------------------------
// K7: sparse decode per window, gathering activations from dense enc
//     (selected entries are unchanged by apply_mask, so order vs K6 is free)
// ---------------------------------------------------------------------------
__global__ __launch_bounds__(256) void decode_win(
    const float* __restrict__ enc,
    const int* __restrict__ idxlist,
    const float* __restrict__ WdT,    // (D_, C_)
    const float* __restrict__ b_dec,
    float* __restrict__ recon)        // (M_, C_)
{
    int row = blockIdx.x;
    int b = row / NW_, w = row % NW_;
    int t0 = b * T_ + w * WIN_;
    __shared__ int sidx[K_];
    __shared__ float act[K_][12];     // stride 12 floats: 16B-aligned, banks spread
    int tid = threadIdx.x;
    if (tid < K_) sidx[tid] = idxlist[(size_t)row * K_ + tid];
    __syncthreads();
    // gather: 256 threads x 4 loads (ci = tid/2, j-half = tid%2)
    {
        int ci = tid >> 1;
        int j4 = (tid & 1) * 4;
        int dd = sidx[ci];
        #pragma unroll
        for (int j = 0; j < 4; j++)
            act[ci][j4 + j] = enc[(size_t)(t0 + j4 + j) * D_ + dd];
    }
    __syncthreads();

    float accv[WIN_][4] = {};
    int c0 = tid * 4;
    for (int i = 0; i < K_; ++i) {
        int d = sidx[i];
        float4 wv = *(const float4*)(WdT + (size_t)d * C_ + c0);
        float4 a03 = *(const float4*)(&act[i][0]);
        float4 a47 = *(const float4*)(&act[i][4]);
        float aj[8] = {a03.x, a03.y, a03.z, a03.w, a47.x, a47.y, a47.z, a47.w};
        #pragma unroll
        for (int j = 0; j < WIN_; j++) {
            accv[j][0] = fmaf(aj[j], wv.x, accv[j][0]);
            accv[j][1] = fmaf(aj[j], wv.y, accv[j][1]);
            accv[j][2] = fmaf(aj[j], wv.z, accv[j][2]);
            accv[j][3] = fmaf(aj[j], wv.w, accv[j][3]);
        }
    }
    float4 bd = *(const float4*)(b_dec + c0);
    #pragma unroll
    for (int j = 0; j < WIN_; j++) {
        float4 o;
        o.x = accv[j][0] + bd.x; o.y = accv[j][1] + bd.y;
        o.z = accv[j][2] + bd.z; o.w = accv[j][3] + bd.w;
        *(float4*)(recon + (size_t)(t0 + j) * C_ + c0) = o;
    }
}

// ---------------------------------------------------------------------------
extern "C" void kernel_launch(void* const* d_in, const int* in_sizes, int n_in,
                              void* d_out, int out_size, void* d_ws, size_t ws_size,
                              hipStream_t stream)
{
    const float* x     = (const float*)d_in[0];
    const float* W_enc = (const float*)d_in[1];
    const float* b_enc = (const float*)d_in[2];
    const float* W_dec = (const float*)d_in[3];
    const float* b_dec = (const float*)d_in[4];

    float* out   = (float*)d_out;
    float* recon = out;                        // M_*C_ floats
    float* enc   = out + (size_t)M_ * C_;      // M_*D_ floats (dense -> masked)

    // scratch inside recon region (dead before decode writes recon)
    unsigned short* xbf   = (unsigned short*)recon;                       // 16.8 MB
    float*          wsums = (float*)((char*)recon + (size_t)M_ * C_ * 2); // 16.8 MB

    // persistent scratch in d_ws
    char* ws = (char*)d_ws;
    float*          WdT     = (float*)ws;                                   // 16.8 MB
    unsigned*       bmask   = (unsigned*)(ws + (size_t)D_ * C_ * 4);        // 512 KB
    int*            idxlist = (int*)((char*)bmask + (size_t)(B_ * NW_) * (D_ / 32) * 4);
    float*          benc2   = (float*)((char*)idxlist + (size_t)(B_ * NW_) * K_ * 4);
    unsigned short* wencbf  = (unsigned short*)((char*)benc2 + D_ * 4);     // 8.4 MB

    prep_benc<<<D_, 256, 0, stream>>>(W_enc, b_enc, b_dec, benc2);
    cvt_bf16<<<(M_ * C_ / 8 + 255) / 256, 256, 0, stream>>>(x, xbf, M_ * C_ / 8);
    cvt_bf16<<<(D_ * C_ / 8 + 255) / 256, 256, 0, stream>>>(W_enc, wencbf, D_ * C_ / 8);
    transpose_wdec<<<dim3(D_ / 32, C_ / 32), dim3(32, 8), 0, stream>>>(W_dec, WdT);
    mfma_gemm_dense<<<dim3(32, 64), 256, 0, stream>>>(xbf, wencbf, benc2, enc, wsums);
    fixup_ws<<<B_ * NW_, 256, 0, stream>>>(wsums, x, W_enc, benc2);
    topk_select<<<B_ * NW_, 256, 0, stream>>>(wsums, bmask, idxlist);
    apply_mask<<<(int)((size_t)M_ * D_ / 4 / 256), 256, 0, stream>>>(enc, bmask);
    decode_win<<<B_ * NW_, 256, 0, stream>>>(enc, idxlist, WdT, b_dec, recon);
}